// Round 6
// baseline (246952.930 us; speedup 1.0000x reference)
//
#include <hip/hip_runtime.h>

// NeuralKalmanFilter scan: 4096 steps x 20 inference iters = 81920 sequential phases.
// R10: parallelize the publish path of R9 (verified: 185ms bench, hbm 11GB, conflicts 0).
//  - pairwise mailbox: wave1->hand[1], wave3->hand[3]; wave0 spins on ONE entry and
//    publishes word 0, wave2 publishes word 1 -- two packers in parallel, each waiting
//    on one producer (R9: one packer waited on three, then packed 2 words serially).
//  - first two poll retries without s_sleep (round-0 was issued ~0.2us earlier; the
//    missing store usually lands within ~0.1us -- sleeping first adds pure latency).
//    Sleep from 3rd retry on (backoff for genuine stragglers preserved).
//  - s_setprio(1) around packer spin->publish (publisher stores are the grid critical
//    path); replica stores issued before the own-LDS float4 write (lane 8 parallel).
// Keeps from R9: 14-bit fixed-point fz (4 vals + 8b tag per u64, 512 words, 2 polled
//  words/thread), ONE __syncthreads/phase, stale-only reload, own-block words skipped,
//  register-resident bf16 weights, 8 replicas, 2 parities, bounded block-uniform abort.

#define SEQL 4096
#define NLAT 2048
#define NOBS 1024
#define NCTL 512

typedef unsigned short u16;
typedef unsigned int   u32;
typedef unsigned long long u64;
typedef float v2f __attribute__((ext_vector_type(2)));

__device__ __forceinline__ float bfl(u32 u)  { return __uint_as_float(u << 16); }
__device__ __forceinline__ float bfh(u32 u)  { return __uint_as_float(u & 0xffff0000u); }
__device__ __forceinline__ float bf2f(u16 s) { return __uint_as_float(((u32)s) << 16); }
__device__ __forceinline__ u16 f2bf(float f) {            // round-to-nearest-even bf16
  u32 x = __float_as_uint(f);
  return (u16)((x + 0x7fffu + ((x >> 16) & 1u)) >> 16);
}
// 14-bit two's-complement fixed point in [-1,1]: q = rint(f*8191)
__device__ __forceinline__ float dq14(u32 u) {
  int q = ((int)(u << 18)) >> 18;                 // sign-extend bit 13
  return (float)q * 1.2208521548046392e-4f;       // 1/8191
}

#if __has_builtin(__builtin_elementwise_fma)
__device__ __forceinline__ v2f pkfma(v2f a, v2f b, v2f c) {
  return __builtin_elementwise_fma(a, b, c);
}
#else
__device__ __forceinline__ v2f pkfma(v2f a, v2f b, v2f c) {
  v2f r; r.x = fmaf(a.x, b.x, c.x); r.y = fmaf(a.y, b.y, c.y); return r;
}
#endif

// Branch-free tanh: tanh(x) = 1 - 2/(exp2(2*log2e*x)+1). Saturates naturally at +-1.
__device__ __forceinline__ float fast_tanh(float x) {
#if __has_builtin(__builtin_amdgcn_exp2f) && __has_builtin(__builtin_amdgcn_rcpf)
  float e = __builtin_amdgcn_exp2f(x * 2.8853900817779268f);
  return 1.f - 2.f * __builtin_amdgcn_rcpf(e + 1.f);
#else
  return tanhf(x);
#endif
}

// DPP butterfly step (quad_perm): CTRL 0xB1 = xor1, 0x4E = xor2.
template <int CTRL>
__device__ __forceinline__ float dpp_add(float x) {
#if __has_builtin(__builtin_amdgcn_update_dpp)
  int y = __builtin_amdgcn_update_dpp(0, __float_as_int(x), CTRL, 0xF, 0xF, true);
  return x + __int_as_float(y);
#else
  return x + __shfl_xor(x, (CTRL == 0xB1) ? 1 : 2, 64);
#endif
}
// Sum over each 32-lane half; every lane gets its half's total.
__device__ __forceinline__ float red32(float x) {
  x = dpp_add<0xB1>(x);
  x = dpp_add<0x4E>(x);
  x += __shfl_xor(x, 4, 64);
  x += __shfl_xor(x, 8, 64);
  x += __shfl_xor(x, 16, 64);
  return x;
}

__device__ __forceinline__ u64 LDW(const u64* p) {
  return __hip_atomic_load(p, __ATOMIC_RELAXED, __HIP_MEMORY_SCOPE_AGENT);
}

// ---------------- elementwise converts ----------------
__global__ void k_f2b(const float* __restrict__ in, u16* __restrict__ out, int n) {
  int i = blockIdx.x * 256 + threadIdx.x;
  if (i < n) out[i] = f2bf(in[i]);
}
__global__ void k_tanh2b(const float* __restrict__ in, u16* __restrict__ out, int n) {
  int i = blockIdx.x * 256 + threadIdx.x;
  if (i < n) out[i] = f2bf(tanhf(in[i]));
}
// out[c*R + r] = bf16(in[r*C + c])   (build Wout^T)
__global__ void k_tr2b(const float* __restrict__ in, u16* __restrict__ out, int R, int C) {
  int i = blockIdx.x * 256 + threadIdx.x;
  if (i < R * C) {
    int r = i / C, c = i % C;
    out[(size_t)c * R + r] = f2bf(in[i]);
  }
}
__global__ void k_zero(u64* __restrict__ p, int n) {
  int i = blockIdx.x * 256 + threadIdx.x;
  if (i < n) p[i] = 0ull;
}

// ---------------- simple LDS-tiled bf16 GEMM (fp32 acc), 64x64 tile ----------------
__global__ __launch_bounds__(256) void gemm_bf16(
    const u16* __restrict__ A, const u16* __restrict__ B,
    float* __restrict__ Cf, u16* __restrict__ Cb, int M, int N, int K)
{
  __shared__ float As[32][68];
  __shared__ float Bs[32][68];
  const int tid = threadIdx.x;
  const int colBase = blockIdx.x * 64, rowBase = blockIdx.y * 64;
  const int tx = tid & 15, ty = tid >> 4;
  const int ar = tid >> 2, ak = (tid & 3) * 8;
  const int bk = tid >> 3, bc = (tid & 7) * 8;
  const u16* Ap = A + (size_t)(rowBase + ar) * K + ak;
  const u16* Bp = B + (size_t)bk * N + colBase + bc;
  float acc[4][4] = {};

  for (int k0 = 0; k0 < K; k0 += 32) {
    uint4 a = *(const uint4*)(Ap + k0);
    uint4 b = *(const uint4*)(Bp + (size_t)k0 * N);
    As[ak + 0][ar] = bfl(a.x); As[ak + 1][ar] = bfh(a.x);
    As[ak + 2][ar] = bfl(a.y); As[ak + 3][ar] = bfh(a.y);
    As[ak + 4][ar] = bfl(a.z); As[ak + 5][ar] = bfh(a.z);
    As[ak + 6][ar] = bfl(a.w); As[ak + 7][ar] = bfh(a.w);
    Bs[bk][bc + 0] = bfl(b.x); Bs[bk][bc + 1] = bfh(b.x);
    Bs[bk][bc + 2] = bfl(b.y); Bs[bk][bc + 3] = bfh(b.y);
    Bs[bk][bc + 4] = bfl(b.z); Bs[bk][bc + 5] = bfh(b.z);
    Bs[bk][bc + 6] = bfl(b.w); Bs[bk][bc + 7] = bfh(b.w);
    __syncthreads();
#pragma unroll
    for (int kk = 0; kk < 32; kk++) {
      float4 av = *(const float4*)&As[kk][ty * 4];
      float4 bv = *(const float4*)&Bs[kk][tx * 4];
      float a4[4] = {av.x, av.y, av.z, av.w};
      float b4[4] = {bv.x, bv.y, bv.z, bv.w};
#pragma unroll
      for (int i = 0; i < 4; i++)
#pragma unroll
        for (int q = 0; q < 4; q++)
          acc[i][q] = fmaf(a4[i], b4[q], acc[i][q]);
    }
    __syncthreads();
  }

  if (Cf) {
#pragma unroll
    for (int i = 0; i < 4; i++) {
      float4 v = make_float4(acc[i][0], acc[i][1], acc[i][2], acc[i][3]);
      *(float4*)&Cf[(size_t)(rowBase + ty * 4 + i) * N + colBase + tx * 4] = v;
    }
  } else {
#pragma unroll
    for (int i = 0; i < 4; i++) {
      u64 pk = (u64)f2bf(acc[i][0]) | ((u64)f2bf(acc[i][1]) << 16) |
               ((u64)f2bf(acc[i][2]) << 32) | ((u64)f2bf(acc[i][3]) << 48);
      *(u64*)&Cb[(size_t)(rowBase + ty * 4 + i) * N + colBase + tx * 4] = pk;
    }
  }
}

// ---------------- the sequential scan (cooperative, 256 blocks x 256 threads) ----------
// Wave wv owns rows bid*8 + wv*2 + {0,1} (lane halves). fzbuf word layout:
// parity[2] x replica[8] x word[512]; word (2*bid+k) = tag8 | q0<<8 | q1<<22 | q2<<36 |
// q3<<50 covering rows 8*bid+4k .. +3 as 14-bit fixed point. Waves 0,2 pack+publish
// word 0,1 respectively (mate waves 1,3 deliver their pair via LDS mailbox).
__global__ void __launch_bounds__(256, 1)
scan_kernel(const u16* __restrict__ G,      // 2048x2048 bf16 (Wout^T Wout)
            const u16* __restrict__ Wr,     // 2048x2048 bf16
            const u16* __restrict__ Bmat,   // 2048x4096 bf16 (Wout^T @ inputs)
            const u16* __restrict__ Cin,    // 2048x4096 bf16 (Win @ tanh(controls))
            float* __restrict__ zs,         // 2048x4096 f32 out
            u16* __restrict__ td,           // 2048x4096 bf16 out: tanh(drive)
            u64* __restrict__ fzbuf,        // 2 parities x 8 replicas x 512 words
            const int* __restrict__ itp, const float* __restrict__ lrp)
{
  __shared__ __align__(16) float fzL[2][NLAT];   // double-buffered fz, fp32
  __shared__ u64 hand[4];                        // mailbox; entries 1,3 used
  __shared__ int sAbort;

  const int tid = threadIdx.x, bid = blockIdx.x;
  const int lane = tid & 63, wv = tid >> 6;
  const int h = lane >> 5;                 // 0: even row of the pair, 1: odd row
  const int chunk = lane & 31;             // column group 0..31
  const int myrow = (bid << 3) + (wv << 1) + h;
  const bool isPub = (wv & 1) == 0;        // waves 0,2 pack+publish
  const int mate = wv | 1;                 // mailbox entry to wait on (1 or 3)
  const int kw = wv >> 1;                  // word index within block (0 or 1)

  const int niters = *itp;       // 20
  const float lr = *lrp;         // 0.05

  // Per-thread weight slice, REGISTER-RESIDENT packed bf16 (uint2 = 4 columns):
  // columns chunk*4 + 128*i + (0..3), i = 0..15. 32 VGPRs per matrix.
  uint2 wGp[16], wWp[16];
  {
    const u16* gRow = G  + (size_t)myrow * NLAT + chunk * 4;
    const u16* wRow = Wr + (size_t)myrow * NLAT + chunk * 4;
#pragma unroll
    for (int i = 0; i < 16; i++) {
      wGp[i] = *(const uint2*)(gRow + 128 * i);
      wWp[i] = *(const uint2*)(wRow + 128 * i);
    }
  }
  for (int i = tid; i < 2 * NLAT; i += 256) (&fzL[0][0])[i] = 0.f;  // z0=0 -> fz=0
  if (tid < 4) hand[tid] = 0ull;    // tag 0 in both halves (phase 1 wants tag 1)
  if (tid == 0) sAbort = 0;

  // Poll words: thread polls 2 strided words (512 total).
  const int w0 = tid, w1 = tid + 256;
  const bool sk0 = (w0 >> 1) == bid, sk1 = (w1 >> 1) == bid;  // own-block words

  // Per-row state, replicated across the 32 lanes of each half-wave.
  float z = 0.f, fz = 0.f, drive = 0.f, bv = 0.f;
  float bvN = bf2f(Bmat[(size_t)myrow * SEQL]);
  float cvN = bf2f(Cin [(size_t)myrow * SEQL]);
  __syncthreads();

  u32 p = 0;
  for (int t = 0; t < SEQL; t++) {
    for (int j = 0; j < niters; j++) {
      p++;
      const int wb = p & 1, rb = wb ^ 1;   // write buffer (this phase), read buffer
      // ---- matvec on fzL[rb] (fz after phase p-1), bf16 weights unpacked in-reg ----
      v2f aG0 = {0.f,0.f}, aG1 = {0.f,0.f}, aG2 = {0.f,0.f}, aG3 = {0.f,0.f};
      const float4* f4 = (const float4*)(&fzL[rb][chunk * 4]);
      float accW = 0.f;
      if (j == 0) {
        v2f aW0 = {0.f,0.f}, aW1 = {0.f,0.f};
#pragma unroll
        for (int i = 0; i < 16; i += 2) {
          float4 va = f4[32 * i], vb = f4[32 * (i + 1)];
          uint2 ga = wGp[i], gb = wGp[i + 1];
          uint2 wa = wWp[i], wbm = wWp[i + 1];
          v2f va0 = {va.x, va.y}, va1 = {va.z, va.w};
          v2f vb0 = {vb.x, vb.y}, vb1 = {vb.z, vb.w};
          aG0 = pkfma((v2f){bfl(ga.x), bfh(ga.x)}, va0, aG0);
          aG1 = pkfma((v2f){bfl(ga.y), bfh(ga.y)}, va1, aG1);
          aG2 = pkfma((v2f){bfl(gb.x), bfh(gb.x)}, vb0, aG2);
          aG3 = pkfma((v2f){bfl(gb.y), bfh(gb.y)}, vb1, aG3);
          aW0 = pkfma((v2f){bfl(wa.x), bfh(wa.x)}, va0, aW0);
          aW0 = pkfma((v2f){bfl(wa.y), bfh(wa.y)}, va1, aW0);
          aW1 = pkfma((v2f){bfl(wbm.x), bfh(wbm.x)}, vb0, aW1);
          aW1 = pkfma((v2f){bfl(wbm.y), bfh(wbm.y)}, vb1, aW1);
        }
        v2f aW = aW0 + aW1;
        accW = red32(aW.x + aW.y);
      } else {
#pragma unroll
        for (int i = 0; i < 16; i += 2) {
          float4 va = f4[32 * i], vb = f4[32 * (i + 1)];
          uint2 ga = wGp[i], gb = wGp[i + 1];
          aG0 = pkfma((v2f){bfl(ga.x), bfh(ga.x)}, (v2f){va.x, va.y}, aG0);
          aG1 = pkfma((v2f){bfl(ga.y), bfh(ga.y)}, (v2f){va.z, va.w}, aG1);
          aG2 = pkfma((v2f){bfl(gb.x), bfh(gb.x)}, (v2f){vb.x, vb.y}, aG2);
          aG3 = pkfma((v2f){bfl(gb.y), bfh(gb.y)}, (v2f){vb.z, vb.w}, aG3);
        }
      }
      v2f aG = (aG0 + aG1) + (aG2 + aG3);
      float accG = red32(aG.x + aG.y);    // all lanes: (G fz)[myrow]

      // ---- z update, replicated per lane ----
      if (j == 0) { bv = bvN; drive = accW + cvN; }
      float corr = bv - accG;                          // (Wout^T(x - Wout fz))[row]
      float dz = (z - drive) - (1.f - fz * fz) * corr;
      z -= lr * dz;
      fz = fast_tanh(z);

      // ---- quantize; mates drop pair into mailbox; pubs spin on ONE entry ----
      const u32 tag8 = p & 0xffu;
      int qi = (int)rintf(fz * 8191.f);                // |fz|<=1 -> |qi|<=8191
      u32 uq = (u32)qi & 0x3FFFu;
      u32 oq = (u32)__shfl_xor((int)uq, 32, 64) & 0x3FFFu;   // other half's row
      if (!isPub) {
        if (lane == 0) {                               // lane0: h=0 -> uq=even, oq=odd
          u64 wd = ((u64)(tag8 | (oq << 8)) << 32) | (u64)(tag8 | (uq << 8));
          __hip_atomic_store(&hand[wv], wd, __ATOMIC_RELAXED,
                             __HIP_MEMORY_SCOPE_WORKGROUP);
        }
      } else {
#if __has_builtin(__builtin_amdgcn_s_setprio)
        __builtin_amdgcn_s_setprio(1);
#endif
        u64 hv;
        for (;;) {                      // local spin; mate arrives within ~100cy
          hv = __hip_atomic_load(&hand[mate], __ATOMIC_RELAXED,
                                 __HIP_MEMORY_SCOPE_WORKGROUP);
          if ((((u32)hv & 0xffu) == tag8) &&
              (((u32)(hv >> 32) & 0xffu) == tag8)) break;
        }
        // lanes 0..8 are h=0: uq = own even row (q0), oq = own odd row (q1)
        u64 q2 = ((u32)hv >> 8) & 0x3FFFu;
        u64 q3 = ((u32)(hv >> 32) >> 8) & 0x3FFFu;
        u64 word = (u64)tag8 | ((u64)uq << 8) | ((u64)oq << 22) | (q2 << 36) | (q3 << 50);
        if (lane < 8)                   // publish to 8 replicas FIRST (critical path)
          __hip_atomic_store(fzbuf + ((size_t)wb * 8 + lane) * 512 + (bid << 1) + kw,
                             word, __ATOMIC_RELAXED, __HIP_MEMORY_SCOPE_AGENT);
        else if (lane == 8)             // own rows straight into LDS (skip own RTT)
          *(float4*)&fzL[wb][((bid << 1) + kw) << 2] =
              make_float4(dq14((u32)(word >> 8)),  dq14((u32)(word >> 22)),
                          dq14((u32)(word >> 36)), dq14((u32)(word >> 50)));
#if __has_builtin(__builtin_amdgcn_s_setprio)
        __builtin_amdgcn_s_setprio(0);
#endif
      }

      // ---- issue poll round 0; aux work overlaps the RTT ----
      const u64* base = fzbuf + ((size_t)wb * 8 + (bid & 7)) * 512;
      u64 g0 = LDW(base + w0), g1 = LDW(base + w1);

      if (j == 0) {
        if (chunk == 0) td[(size_t)myrow * SEQL + t] = f2bf(fast_tanh(drive));
        int tn = t + 1 < SEQL ? t + 1 : t;
        bvN = bf2f(Bmat[(size_t)myrow * SEQL + tn]);
        cvN = bf2f(Cin [(size_t)myrow * SEQL + tn]);
      }
      if (j == niters - 1 && chunk == 0) zs[(size_t)myrow * SEQL + t] = z;

      // ---- check freshest; reload ONLY stale; sleep only from 3rd retry on ----
      int guard = 0;
      for (;;) {
        bool bad0 = !sk0 && ((u32)g0 & 0xffu) != tag8;
        bool bad1 = !sk1 && ((u32)g1 & 0xffu) != tag8;
        if (!(bad0 || bad1)) break;
        if (++guard > 150000) { sAbort = 1; break; }   // bounded abort, no wedge
        if (bad0) g0 = LDW(base + w0);
        if (bad1) g1 = LDW(base + w1);
#if __has_builtin(__builtin_amdgcn_s_sleep)
        if (guard >= 2) __builtin_amdgcn_s_sleep(1);
#endif
      }

      // ---- unpack: word w -> float4 slot w (coalesced, conflict-free) ----
      if (!sk0)
        *(float4*)&fzL[wb][w0 << 2] =
            make_float4(dq14((u32)(g0 >> 8)),  dq14((u32)(g0 >> 22)),
                        dq14((u32)(g0 >> 36)), dq14((u32)(g0 >> 50)));
      if (!sk1)
        *(float4*)&fzL[wb][w1 << 2] =
            make_float4(dq14((u32)(g1 >> 8)),  dq14((u32)(g1 >> 22)),
                        dq14((u32)(g1 >> 36)), dq14((u32)(g1 >> 50)));
      __syncthreads();   // fzL[wb] complete; becomes read buffer next phase
      if (sAbort) return;
    }
  }
}

// ---------------- host ----------------
extern "C" void kernel_launch(void* const* d_in, const int* in_sizes, int n_in,
                              void* d_out, int out_size, void* d_ws, size_t ws_size,
                              hipStream_t stream)
{
  const float* inputs   = (const float*)d_in[0];   // (1024, 4096)
  const float* controls = (const float*)d_in[1];   // (512, 4096)
  const float* Wr       = (const float*)d_in[2];   // (2048, 2048)
  const float* Win      = (const float*)d_in[3];   // (2048, 512)
  const float* Wout     = (const float*)d_in[4];   // (1024, 2048)
  const int*   itp      = (const int*)d_in[5];     // 20
  const float* lrp      = (const float*)d_in[6];   // 0.05
  float* out = (float*)d_out;
  char* ws = (char*)d_ws;

  size_t off = 0;
  u16*   WrB   = (u16*)(ws + off);   off += (size_t)NLAT * NLAT * 2;  // 8 MB
  u16*   Gb    = (u16*)(ws + off);   off += (size_t)NLAT * NLAT * 2;  // 8 MB
  u16*   WoutB = (u16*)(ws + off);   off += (size_t)NOBS * NLAT * 2;  // 4 MB
  u16*   WinB  = (u16*)(ws + off);   off += (size_t)NLAT * NCTL * 2;  // 2 MB
  u16*   XB    = (u16*)(ws + off);   off += (size_t)NOBS * SEQL * 2;  // 8 MB
  u16*   UB    = (u16*)(ws + off);   off += (size_t)NCTL * SEQL * 2;  // 4 MB
  u16*   WoutT = (u16*)(ws + off);   off += (size_t)NLAT * NOBS * 2;  // 4 MB
  u16*   CinB  = (u16*)(ws + off);   off += (size_t)NLAT * SEQL * 2;  // 16 MB
  u16*   TD    = (u16*)(ws + off);   off += (size_t)NLAT * SEQL * 2;  // 16 MB
  u64*   fzbuf = (u64*)(ws + off);   off += (size_t)2 * 8 * 512 * 8;  // 64 KB

  float* zs   = out;                        // (2048, 4096) f32
  float* pred = out + (size_t)NLAT * SEQL;  // (1024, 4096) f32
  u16* BmatB  = (u16*)pred;  // B = Wout^T @ inputs (bf16, 16MB) overlays pred region;
                             // consumed by scan, then overwritten by the final GEMM.

  // Stage 1: converts / transpose / sync-buffer zero (tags must not false-match)
  k_f2b   <<<(NLAT * NLAT + 255) / 256, 256, 0, stream>>>(Wr,    WrB,   NLAT * NLAT);
  k_f2b   <<<(NOBS * NLAT + 255) / 256, 256, 0, stream>>>(Wout,  WoutB, NOBS * NLAT);
  k_f2b   <<<(NLAT * NCTL + 255) / 256, 256, 0, stream>>>(Win,   WinB,  NLAT * NCTL);
  k_f2b   <<<(NOBS * SEQL + 255) / 256, 256, 0, stream>>>(inputs, XB,   NOBS * SEQL);
  k_tanh2b<<<(NCTL * SEQL + 255) / 256, 256, 0, stream>>>(controls, UB, NCTL * SEQL);
  k_tr2b  <<<(NOBS * NLAT + 255) / 256, 256, 0, stream>>>(Wout, WoutT, NOBS, NLAT);
  k_zero  <<<(2 * 8 * 512 + 255) / 256, 256, 0, stream>>>(fzbuf, 2 * 8 * 512);

  // Stage 2: precompute GEMMs (G directly in bf16)
  gemm_bf16<<<dim3(NLAT / 64, NLAT / 64), 256, 0, stream>>>(WoutT, WoutB, nullptr, Gb,
                                                            NLAT, NLAT, NOBS);
  gemm_bf16<<<dim3(SEQL / 64, NLAT / 64), 256, 0, stream>>>(WoutT, XB, nullptr, BmatB,
                                                            NLAT, SEQL, NOBS);
  gemm_bf16<<<dim3(SEQL / 64, NLAT / 64), 256, 0, stream>>>(WinB, UB, nullptr, CinB,
                                                            NLAT, SEQL, NCTL);

  // Stage 3: sequential scan (cooperative so all 256 blocks are co-resident)
  const u16* Gc = Gb; const u16* Wrc = WrB; const u16* Bc = BmatB; const u16* Cc = CinB;
  float* zsp = zs; u16* tdp = TD; u64* fzp = fzbuf;
  const int* it = itp; const float* lr = lrp;
  void* args[9] = { &Gc, &Wrc, &Bc, &Cc, &zsp, &tdp, &fzp, &it, &lr };
  hipLaunchCooperativeKernel((void*)scan_kernel, dim3(NLAT / 8), dim3(256), args, 0, stream);

  // Stage 4: pred_xs = Wout @ tanh(z_projs)
  gemm_bf16<<<dim3(SEQL / 64, NOBS / 64), 256, 0, stream>>>(WoutB, TD, pred, nullptr,
                                                            NOBS, SEQL, NLAT);
}

// Round 7
// 183331.665 us; speedup vs baseline: 1.3470x; 1.3470x over previous
//
#include <hip/hip_runtime.h>

// NeuralKalmanFilter scan: 4096 steps x 20 inference iters = 81920 sequential phases.
// R11: shrink the broadcast to its floor. Session law: phase time tracks
// (sync words) x (publisher events): 768->1024 hurt (R8), 1024->512+1pub helped (R9,
// 185ms), splitting the publisher hurt (R10, 247ms). R11: 7-bit fixed point fz with
// ERROR FEEDBACK (residual carried per-row, replicated deterministically) -> all 8 rows
// of a block + 8-bit tag in ONE u64. 256 words total, word index == bid:
//  - each thread polls exactly ONE word (skips own block's);
//  - publisher wave packs ONE word, 8 lanes store 8 replicas = ONE store instruction;
//  - unpack: 1 word -> 8 floats -> two ds_write_b128.
// Error-feedback accuracy arithmetic: step 1/63 -> elem err std 4.6e-3; through G/Wr
// (row norms ~0.9) -> z/drive noise ~0.005 -> absmax adds ~0.025 on top of the bf16
// floor 0.0156; expect 0.03-0.045 < 0.06 threshold.
// R10 lessons reverted: single publisher wave, sleep on EVERY retry, no setprio
// (1 wave/SIMD at this occupancy -> setprio is a no-op).
// Keeps from R9: LDS mailbox handoff, ONE __syncthreads/phase, issue-poll-then-aux,
// stale-only reload, own rows written straight to LDS, register-resident bf16 weights,
// 8 replicas, 2 parities, bounded block-uniform abort.

#define SEQL 4096
#define NLAT 2048
#define NOBS 1024
#define NCTL 512

typedef unsigned short u16;
typedef unsigned int   u32;
typedef unsigned long long u64;
typedef float v2f __attribute__((ext_vector_type(2)));

__device__ __forceinline__ float bfl(u32 u)  { return __uint_as_float(u << 16); }
__device__ __forceinline__ float bfh(u32 u)  { return __uint_as_float(u & 0xffff0000u); }
__device__ __forceinline__ float bf2f(u16 s) { return __uint_as_float(((u32)s) << 16); }
__device__ __forceinline__ u16 f2bf(float f) {            // round-to-nearest-even bf16
  u32 x = __float_as_uint(f);
  return (u16)((x + 0x7fffu + ((x >> 16) & 1u)) >> 16);
}
// 7-bit two's-complement fixed point in [-1,1]: q = clamp(rint(f*63), -63, 63)
__device__ __forceinline__ float dq7(u32 u) {
  int q = ((int)(u << 25)) >> 25;                 // sign-extend bit 6
  return (float)q * 0.015873015873015872f;        // 1/63
}

#if __has_builtin(__builtin_elementwise_fma)
__device__ __forceinline__ v2f pkfma(v2f a, v2f b, v2f c) {
  return __builtin_elementwise_fma(a, b, c);
}
#else
__device__ __forceinline__ v2f pkfma(v2f a, v2f b, v2f c) {
  v2f r; r.x = fmaf(a.x, b.x, c.x); r.y = fmaf(a.y, b.y, c.y); return r;
}
#endif

// Branch-free tanh: tanh(x) = 1 - 2/(exp2(2*log2e*x)+1). Saturates naturally at +-1.
__device__ __forceinline__ float fast_tanh(float x) {
#if __has_builtin(__builtin_amdgcn_exp2f) && __has_builtin(__builtin_amdgcn_rcpf)
  float e = __builtin_amdgcn_exp2f(x * 2.8853900817779268f);
  return 1.f - 2.f * __builtin_amdgcn_rcpf(e + 1.f);
#else
  return tanhf(x);
#endif
}

// DPP butterfly step (quad_perm): CTRL 0xB1 = xor1, 0x4E = xor2.
template <int CTRL>
__device__ __forceinline__ float dpp_add(float x) {
#if __has_builtin(__builtin_amdgcn_update_dpp)
  int y = __builtin_amdgcn_update_dpp(0, __float_as_int(x), CTRL, 0xF, 0xF, true);
  return x + __int_as_float(y);
#else
  return x + __shfl_xor(x, (CTRL == 0xB1) ? 1 : 2, 64);
#endif
}
// Sum over each 32-lane half; every lane gets its half's total.
__device__ __forceinline__ float red32(float x) {
  x = dpp_add<0xB1>(x);
  x = dpp_add<0x4E>(x);
  x += __shfl_xor(x, 4, 64);
  x += __shfl_xor(x, 8, 64);
  x += __shfl_xor(x, 16, 64);
  return x;
}

__device__ __forceinline__ u64 LDW(const u64* p) {
  return __hip_atomic_load(p, __ATOMIC_RELAXED, __HIP_MEMORY_SCOPE_AGENT);
}
__device__ __forceinline__ u64 LDH(const u64* p) {
  return __hip_atomic_load(p, __ATOMIC_RELAXED, __HIP_MEMORY_SCOPE_WORKGROUP);
}

// ---------------- elementwise converts ----------------
__global__ void k_f2b(const float* __restrict__ in, u16* __restrict__ out, int n) {
  int i = blockIdx.x * 256 + threadIdx.x;
  if (i < n) out[i] = f2bf(in[i]);
}
__global__ void k_tanh2b(const float* __restrict__ in, u16* __restrict__ out, int n) {
  int i = blockIdx.x * 256 + threadIdx.x;
  if (i < n) out[i] = f2bf(tanhf(in[i]));
}
// out[c*R + r] = bf16(in[r*C + c])   (build Wout^T)
__global__ void k_tr2b(const float* __restrict__ in, u16* __restrict__ out, int R, int C) {
  int i = blockIdx.x * 256 + threadIdx.x;
  if (i < R * C) {
    int r = i / C, c = i % C;
    out[(size_t)c * R + r] = f2bf(in[i]);
  }
}
__global__ void k_zero(u64* __restrict__ p, int n) {
  int i = blockIdx.x * 256 + threadIdx.x;
  if (i < n) p[i] = 0ull;
}

// ---------------- simple LDS-tiled bf16 GEMM (fp32 acc), 64x64 tile ----------------
__global__ __launch_bounds__(256) void gemm_bf16(
    const u16* __restrict__ A, const u16* __restrict__ B,
    float* __restrict__ Cf, u16* __restrict__ Cb, int M, int N, int K)
{
  __shared__ float As[32][68];
  __shared__ float Bs[32][68];
  const int tid = threadIdx.x;
  const int colBase = blockIdx.x * 64, rowBase = blockIdx.y * 64;
  const int tx = tid & 15, ty = tid >> 4;
  const int ar = tid >> 2, ak = (tid & 3) * 8;
  const int bk = tid >> 3, bc = (tid & 7) * 8;
  const u16* Ap = A + (size_t)(rowBase + ar) * K + ak;
  const u16* Bp = B + (size_t)bk * N + colBase + bc;
  float acc[4][4] = {};

  for (int k0 = 0; k0 < K; k0 += 32) {
    uint4 a = *(const uint4*)(Ap + k0);
    uint4 b = *(const uint4*)(Bp + (size_t)k0 * N);
    As[ak + 0][ar] = bfl(a.x); As[ak + 1][ar] = bfh(a.x);
    As[ak + 2][ar] = bfl(a.y); As[ak + 3][ar] = bfh(a.y);
    As[ak + 4][ar] = bfl(a.z); As[ak + 5][ar] = bfh(a.z);
    As[ak + 6][ar] = bfl(a.w); As[ak + 7][ar] = bfh(a.w);
    Bs[bk][bc + 0] = bfl(b.x); Bs[bk][bc + 1] = bfh(b.x);
    Bs[bk][bc + 2] = bfl(b.y); Bs[bk][bc + 3] = bfh(b.y);
    Bs[bk][bc + 4] = bfl(b.z); Bs[bk][bc + 5] = bfh(b.z);
    Bs[bk][bc + 6] = bfl(b.w); Bs[bk][bc + 7] = bfh(b.w);
    __syncthreads();
#pragma unroll
    for (int kk = 0; kk < 32; kk++) {
      float4 av = *(const float4*)&As[kk][ty * 4];
      float4 bv = *(const float4*)&Bs[kk][tx * 4];
      float a4[4] = {av.x, av.y, av.z, av.w};
      float b4[4] = {bv.x, bv.y, bv.z, bv.w};
#pragma unroll
      for (int i = 0; i < 4; i++)
#pragma unroll
        for (int q = 0; q < 4; q++)
          acc[i][q] = fmaf(a4[i], b4[q], acc[i][q]);
    }
    __syncthreads();
  }

  if (Cf) {
#pragma unroll
    for (int i = 0; i < 4; i++) {
      float4 v = make_float4(acc[i][0], acc[i][1], acc[i][2], acc[i][3]);
      *(float4*)&Cf[(size_t)(rowBase + ty * 4 + i) * N + colBase + tx * 4] = v;
    }
  } else {
#pragma unroll
    for (int i = 0; i < 4; i++) {
      u64 pk = (u64)f2bf(acc[i][0]) | ((u64)f2bf(acc[i][1]) << 16) |
               ((u64)f2bf(acc[i][2]) << 32) | ((u64)f2bf(acc[i][3]) << 48);
      *(u64*)&Cb[(size_t)(rowBase + ty * 4 + i) * N + colBase + tx * 4] = pk;
    }
  }
}

// ---------------- the sequential scan (cooperative, 256 blocks x 256 threads) ----------
// Wave wv owns rows bid*8 + wv*2 + {0,1} (lane halves). fzbuf word layout:
// parity[2] x replica[8] x word[256]; word bid = tag8 | q0<<8 | q1<<15 | ... | q7<<57
// covering rows 8*bid..8*bid+7 as 7-bit fixed point (error-feedback quantized).
__global__ void __launch_bounds__(256, 1)
scan_kernel(const u16* __restrict__ G,      // 2048x2048 bf16 (Wout^T Wout)
            const u16* __restrict__ Wr,     // 2048x2048 bf16
            const u16* __restrict__ Bmat,   // 2048x4096 bf16 (Wout^T @ inputs)
            const u16* __restrict__ Cin,    // 2048x4096 bf16 (Win @ tanh(controls))
            float* __restrict__ zs,         // 2048x4096 f32 out
            u16* __restrict__ td,           // 2048x4096 bf16 out: tanh(drive)
            u64* __restrict__ fzbuf,        // 2 parities x 8 replicas x 256 words
            const int* __restrict__ itp, const float* __restrict__ lrp)
{
  __shared__ __align__(16) float fzL[2][NLAT];   // double-buffered fz, fp32
  __shared__ u64 hand[4];                        // per-wave mailbox (block-local)
  __shared__ int sAbort;

  const int tid = threadIdx.x, bid = blockIdx.x;
  const int lane = tid & 63, wv = tid >> 6;
  const int h = lane >> 5;                 // 0: even row of the pair, 1: odd row
  const int chunk = lane & 31;             // column group 0..31
  const int myrow = (bid << 3) + (wv << 1) + h;

  const int niters = *itp;       // 20
  const float lr = *lrp;         // 0.05

  // Per-thread weight slice, REGISTER-RESIDENT packed bf16 (uint2 = 4 columns):
  // columns chunk*4 + 128*i + (0..3), i = 0..15. 32 VGPRs per matrix.
  uint2 wGp[16], wWp[16];
  {
    const u16* gRow = G  + (size_t)myrow * NLAT + chunk * 4;
    const u16* wRow = Wr + (size_t)myrow * NLAT + chunk * 4;
#pragma unroll
    for (int i = 0; i < 16; i++) {
      wGp[i] = *(const uint2*)(gRow + 128 * i);
      wWp[i] = *(const uint2*)(wRow + 128 * i);
    }
  }
  for (int i = tid; i < 2 * NLAT; i += 256) (&fzL[0][0])[i] = 0.f;  // z0=0 -> fz=0
  if (tid < 4) hand[tid] = 0ull;    // tag 0 in both halves (phase 1 wants tag 1)
  if (tid == 0) sAbort = 0;

  // Poll: thread polls ONE word (256 total); word index == publisher block id.
  const bool sk0 = (tid == bid);

  // Per-row state, replicated across the 32 lanes of each half-wave.
  float z = 0.f, fz = 0.f, drive = 0.f, bv = 0.f, eq = 0.f;
  float bvN = bf2f(Bmat[(size_t)myrow * SEQL]);
  float cvN = bf2f(Cin [(size_t)myrow * SEQL]);
  __syncthreads();

  u32 p = 0;
  for (int t = 0; t < SEQL; t++) {
    for (int j = 0; j < niters; j++) {
      p++;
      const int wb = p & 1, rb = wb ^ 1;   // write buffer (this phase), read buffer
      // ---- matvec on fzL[rb] (fz after phase p-1), bf16 weights unpacked in-reg ----
      v2f aG0 = {0.f,0.f}, aG1 = {0.f,0.f}, aG2 = {0.f,0.f}, aG3 = {0.f,0.f};
      const float4* f4 = (const float4*)(&fzL[rb][chunk * 4]);
      float accW = 0.f;
      if (j == 0) {
        v2f aW0 = {0.f,0.f}, aW1 = {0.f,0.f};
#pragma unroll
        for (int i = 0; i < 16; i += 2) {
          float4 va = f4[32 * i], vb = f4[32 * (i + 1)];
          uint2 ga = wGp[i], gb = wGp[i + 1];
          uint2 wa = wWp[i], wbm = wWp[i + 1];
          v2f va0 = {va.x, va.y}, va1 = {va.z, va.w};
          v2f vb0 = {vb.x, vb.y}, vb1 = {vb.z, vb.w};
          aG0 = pkfma((v2f){bfl(ga.x), bfh(ga.x)}, va0, aG0);
          aG1 = pkfma((v2f){bfl(ga.y), bfh(ga.y)}, va1, aG1);
          aG2 = pkfma((v2f){bfl(gb.x), bfh(gb.x)}, vb0, aG2);
          aG3 = pkfma((v2f){bfl(gb.y), bfh(gb.y)}, vb1, aG3);
          aW0 = pkfma((v2f){bfl(wa.x), bfh(wa.x)}, va0, aW0);
          aW0 = pkfma((v2f){bfl(wa.y), bfh(wa.y)}, va1, aW0);
          aW1 = pkfma((v2f){bfl(wbm.x), bfh(wbm.x)}, vb0, aW1);
          aW1 = pkfma((v2f){bfl(wbm.y), bfh(wbm.y)}, vb1, aW1);
        }
        v2f aW = aW0 + aW1;
        accW = red32(aW.x + aW.y);
      } else {
#pragma unroll
        for (int i = 0; i < 16; i += 2) {
          float4 va = f4[32 * i], vb = f4[32 * (i + 1)];
          uint2 ga = wGp[i], gb = wGp[i + 1];
          aG0 = pkfma((v2f){bfl(ga.x), bfh(ga.x)}, (v2f){va.x, va.y}, aG0);
          aG1 = pkfma((v2f){bfl(ga.y), bfh(ga.y)}, (v2f){va.z, va.w}, aG1);
          aG2 = pkfma((v2f){bfl(gb.x), bfh(gb.x)}, (v2f){vb.x, vb.y}, aG2);
          aG3 = pkfma((v2f){bfl(gb.y), bfh(gb.y)}, (v2f){vb.z, vb.w}, aG3);
        }
      }
      v2f aG = (aG0 + aG1) + (aG2 + aG3);
      float accG = red32(aG.x + aG.y);    // all lanes: (G fz)[myrow]

      // ---- z update, replicated per lane ----
      if (j == 0) { bv = bvN; drive = accW + cvN; }
      float corr = bv - accG;                          // (Wout^T(x - Wout fz))[row]
      float dz = (z - drive) - (1.f - fz * fz) * corr;
      z -= lr * dz;
      fz = fast_tanh(z);

      // ---- 7-bit quantize with error feedback (replicated -> deterministic) ----
      const u32 tag8 = p & 0xffu;
      float xq = fz + eq;
      int qi = (int)rintf(xq * 63.f);
      qi = qi > 63 ? 63 : (qi < -63 ? -63 : qi);
      eq = xq - (float)qi * 0.015873015873015872f;
      u32 uq = (u32)qi & 0x7Fu;
      u32 oq = (u32)__shfl_xor((int)uq, 32, 64) & 0x7Fu;   // other half's row
      u32 qe = h ? oq : uq;        // even row's code
      u32 qo = h ? uq : oq;        // odd row's code
      if (lane == 0) {             // mailbox: tag duplicated in both 32b halves
        u64 wd = ((u64)(tag8 | (qo << 8)) << 32) | (u64)(tag8 | (qe << 8));
        __hip_atomic_store(&hand[wv], wd, __ATOMIC_RELAXED,
                           __HIP_MEMORY_SCOPE_WORKGROUP);
      }
      asm volatile("" ::: "memory");   // keep mailbox write before poll issue

      // ---- wave 0: gather mailbox, pack ONE word, publish to 8 replicas ----
      if (wv == 0) {
        for (;;) {                      // local spin; waves arrive within ~100cy
          u64 hv = LDH(&hand[lane & 3]);
          bool ok = (((u32)hv & 0xffu) == tag8) && (((u32)(hv >> 32) & 0xffu) == tag8);
          if (__all(ok)) break;
        }
        if (lane < 10) {
          u64 h0 = LDH(&hand[0]), h1 = LDH(&hand[1]);
          u64 h2 = LDH(&hand[2]), h3 = LDH(&hand[3]);
          u64 word = (u64)tag8
            | (((h0 >> 8) & 0x7Fu) << 8)  | (((h0 >> 40) & 0x7Fu) << 15)
            | (((h1 >> 8) & 0x7Fu) << 22) | (((h1 >> 40) & 0x7Fu) << 29)
            | (((h2 >> 8) & 0x7Fu) << 36) | (((h2 >> 40) & 0x7Fu) << 43)
            | (((h3 >> 8) & 0x7Fu) << 50) | (((h3 >> 40) & 0x7Fu) << 57);
          if (lane < 8) {               // ONE store instruction: 8 lanes x 8B
            __hip_atomic_store(fzbuf + ((size_t)wb * 8 + lane) * 256 + bid,
                               word, __ATOMIC_RELAXED, __HIP_MEMORY_SCOPE_AGENT);
          } else {                      // lanes 8,9: own rows straight into LDS
            int q4 = lane - 8;          // half index 0/1
            u32 sh = 8 + 28 * q4;
            *(float4*)&fzL[wb][(bid << 3) + (q4 << 2)] =
                make_float4(dq7((u32)(word >> sh)),        dq7((u32)(word >> (sh + 7))),
                            dq7((u32)(word >> (sh + 14))), dq7((u32)(word >> (sh + 21))));
          }
        }
      }

      // ---- issue poll round 0; aux work overlaps the RTT ----
      const u64* base = fzbuf + ((size_t)wb * 8 + (bid & 7)) * 256;
      u64 g0 = LDW(base + tid);

      if (j == 0) {
        if (chunk == 0) td[(size_t)myrow * SEQL + t] = f2bf(fast_tanh(drive));
        int tn = t + 1 < SEQL ? t + 1 : t;
        bvN = bf2f(Bmat[(size_t)myrow * SEQL + tn]);
        cvN = bf2f(Cin [(size_t)myrow * SEQL + tn]);
      }
      if (j == niters - 1 && chunk == 0) zs[(size_t)myrow * SEQL + t] = z;

      // ---- check freshest; reload if stale; sleep; recheck ----
      int guard = 0;
      for (;;) {
        if (sk0 || ((u32)g0 & 0xffu) == tag8) break;
        if (++guard > 150000) { sAbort = 1; break; }   // bounded abort, no wedge
        g0 = LDW(base + tid);
#if __has_builtin(__builtin_amdgcn_s_sleep)
        __builtin_amdgcn_s_sleep(1);
#endif
      }

      // ---- unpack: word tid -> 8 floats -> fzL[wb][8*tid..8*tid+7] ----
      if (!sk0) {
        *(float4*)&fzL[wb][tid << 3] =
            make_float4(dq7((u32)(g0 >> 8)),  dq7((u32)(g0 >> 15)),
                        dq7((u32)(g0 >> 22)), dq7((u32)(g0 >> 29)));
        *(float4*)&fzL[wb][(tid << 3) + 4] =
            make_float4(dq7((u32)(g0 >> 36)), dq7((u32)(g0 >> 43)),
                        dq7((u32)(g0 >> 50)), dq7((u32)(g0 >> 57)));
      }
      __syncthreads();   // fzL[wb] complete; becomes read buffer next phase
      if (sAbort) return;
    }
  }
}

// ---------------- host ----------------
extern "C" void kernel_launch(void* const* d_in, const int* in_sizes, int n_in,
                              void* d_out, int out_size, void* d_ws, size_t ws_size,
                              hipStream_t stream)
{
  const float* inputs   = (const float*)d_in[0];   // (1024, 4096)
  const float* controls = (const float*)d_in[1];   // (512, 4096)
  const float* Wr       = (const float*)d_in[2];   // (2048, 2048)
  const float* Win      = (const float*)d_in[3];   // (2048, 512)
  const float* Wout     = (const float*)d_in[4];   // (1024, 2048)
  const int*   itp      = (const int*)d_in[5];     // 20
  const float* lrp      = (const float*)d_in[6];   // 0.05
  float* out = (float*)d_out;
  char* ws = (char*)d_ws;

  size_t off = 0;
  u16*   WrB   = (u16*)(ws + off);   off += (size_t)NLAT * NLAT * 2;  // 8 MB
  u16*   Gb    = (u16*)(ws + off);   off += (size_t)NLAT * NLAT * 2;  // 8 MB
  u16*   WoutB = (u16*)(ws + off);   off += (size_t)NOBS * NLAT * 2;  // 4 MB
  u16*   WinB  = (u16*)(ws + off);   off += (size_t)NLAT * NCTL * 2;  // 2 MB
  u16*   XB    = (u16*)(ws + off);   off += (size_t)NOBS * SEQL * 2;  // 8 MB
  u16*   UB    = (u16*)(ws + off);   off += (size_t)NCTL * SEQL * 2;  // 4 MB
  u16*   WoutT = (u16*)(ws + off);   off += (size_t)NLAT * NOBS * 2;  // 4 MB
  u16*   CinB  = (u16*)(ws + off);   off += (size_t)NLAT * SEQL * 2;  // 16 MB
  u16*   TD    = (u16*)(ws + off);   off += (size_t)NLAT * SEQL * 2;  // 16 MB
  u64*   fzbuf = (u64*)(ws + off);   off += (size_t)2 * 8 * 256 * 8;  // 32 KB

  float* zs   = out;                        // (2048, 4096) f32
  float* pred = out + (size_t)NLAT * SEQL;  // (1024, 4096) f32
  u16* BmatB  = (u16*)pred;  // B = Wout^T @ inputs (bf16, 16MB) overlays pred region;
                             // consumed by scan, then overwritten by the final GEMM.

  // Stage 1: converts / transpose / sync-buffer zero (tags must not false-match)
  k_f2b   <<<(NLAT * NLAT + 255) / 256, 256, 0, stream>>>(Wr,    WrB,   NLAT * NLAT);
  k_f2b   <<<(NOBS * NLAT + 255) / 256, 256, 0, stream>>>(Wout,  WoutB, NOBS * NLAT);
  k_f2b   <<<(NLAT * NCTL + 255) / 256, 256, 0, stream>>>(Win,   WinB,  NLAT * NCTL);
  k_f2b   <<<(NOBS * SEQL + 255) / 256, 256, 0, stream>>>(inputs, XB,   NOBS * SEQL);
  k_tanh2b<<<(NCTL * SEQL + 255) / 256, 256, 0, stream>>>(controls, UB, NCTL * SEQL);
  k_tr2b  <<<(NOBS * NLAT + 255) / 256, 256, 0, stream>>>(Wout, WoutT, NOBS, NLAT);
  k_zero  <<<(2 * 8 * 256 + 255) / 256, 256, 0, stream>>>(fzbuf, 2 * 8 * 256);

  // Stage 2: precompute GEMMs (G directly in bf16)
  gemm_bf16<<<dim3(NLAT / 64, NLAT / 64), 256, 0, stream>>>(WoutT, WoutB, nullptr, Gb,
                                                            NLAT, NLAT, NOBS);
  gemm_bf16<<<dim3(SEQL / 64, NLAT / 64), 256, 0, stream>>>(WoutT, XB, nullptr, BmatB,
                                                            NLAT, SEQL, NOBS);
  gemm_bf16<<<dim3(SEQL / 64, NLAT / 64), 256, 0, stream>>>(WinB, UB, nullptr, CinB,
                                                            NLAT, SEQL, NCTL);

  // Stage 3: sequential scan (cooperative so all 256 blocks are co-resident)
  const u16* Gc = Gb; const u16* Wrc = WrB; const u16* Bc = BmatB; const u16* Cc = CinB;
  float* zsp = zs; u16* tdp = TD; u64* fzp = fzbuf;
  const int* it = itp; const float* lr = lrp;
  void* args[9] = { &Gc, &Wrc, &Bc, &Cc, &zsp, &tdp, &fzp, &it, &lr };
  hipLaunchCooperativeKernel((void*)scan_kernel, dim3(NLAT / 8), dim3(256), args, 0, stream);

  // Stage 4: pred_xs = Wout @ tanh(z_projs)
  gemm_bf16<<<dim3(SEQL / 64, NOBS / 64), 256, 0, stream>>>(WoutB, TD, pred, nullptr,
                                                            NOBS, SEQL, NLAT);
}